// Round 1
// baseline (536.991 us; speedup 1.0000x reference)
//
#include <hip/hip_runtime.h>

// TimeTempTransformerModule: MLP(1->16->32) -> biGRU(H=32, SEQ=32) -> meanpool -> dec(64->128)
// B = 32768 batch rows, all fp32.
//
// Mapping: 32 lanes per batch row (wave = 2 rows). Lane j owns hidden unit j:
//   - registers hold w_hh rows {j, 32+j, 64+j} (96 VGPR) and Wc rows (48 VGPR)
//   - h_k broadcast via ds_bpermute within the 32-lane group
//   - h1[16] (post-leakyrelu MLP hidden) precomputed per block into LDS,
//     read with group-uniform (broadcast) ds_read_b128
// Precompute kernel folds w_ih through the second linear layer:
//   Wc = w_ih @ w2  [96x16],  bc = w_ih @ b2 + b_ih  [96]   (per direction)

#define SEQB 32
#define NH   16   // MLP hidden
#define DH   32   // GRU hidden

__device__ __forceinline__ float fast_sigmoid(float v) {
    return __builtin_amdgcn_rcpf(1.0f + __expf(-v));
}
__device__ __forceinline__ float fast_tanh(float v) {
    // tanh(v) = 1 - 2/(exp(2v)+1)
    return fmaf(-2.0f, __builtin_amdgcn_rcpf(1.0f + __expf(2.0f * v)), 1.0f);
}

// ws layout (floats): [dir0: Wc 96*16 | bc 96][dir1: Wc 96*16 | bc 96]
#define WS_STRIDE 1632

__global__ __launch_bounds__(192) void gru_precompute_kernel(
    const float* __restrict__ w_ih_f, const float* __restrict__ b_ih_f,
    const float* __restrict__ w_ih_b, const float* __restrict__ b_ih_b,
    const float* __restrict__ w2, const float* __restrict__ b2,
    float* __restrict__ ws)
{
    const int t   = threadIdx.x;
    const int dir = t / 96;
    const int g   = t % 96;
    const float* wih = dir ? w_ih_b : w_ih_f;
    const float* bih = dir ? b_ih_b : b_ih_f;
    float* Wc = ws + dir * WS_STRIDE;
    float* bc = Wc + 96 * NH;

    float acc[NH];
#pragma unroll
    for (int m = 0; m < NH; ++m) acc[m] = 0.0f;
    float accb = bih[g];
    for (int d = 0; d < DH; ++d) {
        float wv = wih[g * DH + d];
        accb = fmaf(wv, b2[d], accb);
#pragma unroll
        for (int m = 0; m < NH; ++m) acc[m] = fmaf(wv, w2[d * NH + m], acc[m]);
    }
#pragma unroll
    for (int m = 0; m < NH; ++m) Wc[g * NH + m] = acc[m];
    bc[g] = accb;
}

__global__ __launch_bounds__(256, 2) void gru_main_kernel(
    const float* __restrict__ x,
    const float* __restrict__ w1, const float* __restrict__ b1,
    const float* __restrict__ whh_f, const float* __restrict__ bhh_f,
    const float* __restrict__ whh_b, const float* __restrict__ bhh_b,
    const float* __restrict__ wsbuf,
    const float* __restrict__ w_dec, const float* __restrict__ b_dec,
    float* __restrict__ out)
{
    __shared__ __align__(16) float lds_h1[8 * SEQB * NH]; // 16 KB
    __shared__ __align__(16) float lds_p[8 * 64];         // 2 KB

    const int tid = threadIdx.x;
    const int j   = tid & 31;   // hidden unit owned by this lane
    const int bl  = tid >> 5;   // batch row within block (0..7)

    // ---- Phase 1: per-block h1 table. thread <-> (b = tid>>5, s = tid&31) ----
    {
        float xs = x[(size_t)blockIdx.x * 256 + tid]; // coalesced: x is [B][32]
        float tv[NH];
#pragma unroll
        for (int m = 0; m < NH; ++m) {
            float t = fmaf(xs, w1[m], b1[m]);
            tv[m] = t > 0.0f ? t : 0.01f * t; // leaky_relu(0.01)
        }
        float4* dst = (float4*)&lds_h1[tid * NH];
#pragma unroll
        for (int q = 0; q < 4; ++q)
            dst[q] = make_float4(tv[4 * q], tv[4 * q + 1], tv[4 * q + 2], tv[4 * q + 3]);
    }
    __syncthreads();

    const float* h1base = &lds_h1[bl * (SEQB * NH)];
    const int lanebase = (tid & 32) << 2; // byte index of group base for bpermute

    float poolf = 0.0f, poolb = 0.0f;

#pragma unroll 1
    for (int dir = 0; dir < 2; ++dir) {
        const float* whh = dir ? whh_b : whh_f;
        const float* bhh = dir ? bhh_b : bhh_f;
        const float* Wc  = wsbuf + dir * WS_STRIDE;
        const float* bc  = Wc + 96 * NH;

        // per-lane weight rows -> registers
        float wr[DH], wz[DH], wn[DH];
        {
            const float4* p0 = (const float4*)(whh + (j) * DH);
            const float4* p1 = (const float4*)(whh + (32 + j) * DH);
            const float4* p2 = (const float4*)(whh + (64 + j) * DH);
#pragma unroll
            for (int q = 0; q < 8; ++q) {
                float4 v0 = p0[q]; wr[4*q]=v0.x; wr[4*q+1]=v0.y; wr[4*q+2]=v0.z; wr[4*q+3]=v0.w;
                float4 v1 = p1[q]; wz[4*q]=v1.x; wz[4*q+1]=v1.y; wz[4*q+2]=v1.z; wz[4*q+3]=v1.w;
                float4 v2 = p2[q]; wn[4*q]=v2.x; wn[4*q+1]=v2.y; wn[4*q+2]=v2.z; wn[4*q+3]=v2.w;
            }
        }
        float cr[NH], cz[NH], cn[NH];
        {
            const float4* p0 = (const float4*)(Wc + (j) * NH);
            const float4* p1 = (const float4*)(Wc + (32 + j) * NH);
            const float4* p2 = (const float4*)(Wc + (64 + j) * NH);
#pragma unroll
            for (int q = 0; q < 4; ++q) {
                float4 v0 = p0[q]; cr[4*q]=v0.x; cr[4*q+1]=v0.y; cr[4*q+2]=v0.z; cr[4*q+3]=v0.w;
                float4 v1 = p1[q]; cz[4*q]=v1.x; cz[4*q+1]=v1.y; cz[4*q+2]=v1.z; cz[4*q+3]=v1.w;
                float4 v2 = p2[q]; cn[4*q]=v2.x; cn[4*q+1]=v2.y; cn[4*q+2]=v2.z; cn[4*q+3]=v2.w;
            }
        }
        const float br  = bc[j]      + bhh[j];       // r bias (gx + gh)
        const float bz  = bc[32 + j] + bhh[32 + j];  // z bias
        const float bnx = bc[64 + j];                // n bias, gx part
        const float bnh = bhh[64 + j];               // n bias, gh part (inside r*gh_n)

        float h = 0.0f, pool = 0.0f;

#pragma unroll 1
        for (int ss = 0; ss < SEQB; ++ss) {
            const int s = dir ? (SEQB - 1 - ss) : ss;

            // h1[s][0..15] : group-uniform LDS reads (broadcast)
            const float4* h1p = (const float4*)(h1base + s * NH);
            float4 A0 = h1p[0], A1 = h1p[1], A2 = h1p[2], A3 = h1p[3];
            float h1v[NH] = {A0.x,A0.y,A0.z,A0.w, A1.x,A1.y,A1.z,A1.w,
                             A2.x,A2.y,A2.z,A2.w, A3.x,A3.y,A3.z,A3.w};

            // gx (folded through Wc)
            float ar = br, az = bz, an = bnx;
#pragma unroll
            for (int m = 0; m < NH; ++m) {
                ar = fmaf(cr[m], h1v[m], ar);
                az = fmaf(cz[m], h1v[m], az);
                an = fmaf(cn[m], h1v[m], an);
            }

            // gh: broadcast h_k from lane k of this 32-lane group
            float gr = 0.0f, gz = 0.0f, gn = bnh;
            const int hbits = __float_as_int(h);
#pragma unroll
            for (int k = 0; k < DH; ++k) {
                float hk = __int_as_float(
                    __builtin_amdgcn_ds_bpermute(lanebase + 4 * k, hbits));
                gr = fmaf(wr[k], hk, gr);
                gz = fmaf(wz[k], hk, gz);
                gn = fmaf(wn[k], hk, gn);
            }

            float r = fast_sigmoid(ar + gr);
            float z = fast_sigmoid(az + gz);
            float n = fast_tanh(fmaf(r, gn, an));
            h = fmaf(z, h - n, n); // (1-z)*n + z*h
            pool += h;
        }
        if (dir == 0) poolf = pool * (1.0f / 32.0f);
        else          poolb = pool * (1.0f / 32.0f);
    }

    // ---- Decoder: pooled[64] @ w_dec.T + b_dec ----
    lds_p[bl * 64 + j]      = poolf;
    lds_p[bl * 64 + 32 + j] = poolb;
    __syncthreads();

    {
        const int obase = (tid & 31) << 2; // 4 outputs per thread
        const int bb    = tid >> 5;
        const float4* p4 = (const float4*)&lds_p[bb * 64];
        const float4* r0 = (const float4*)(w_dec + (size_t)(obase + 0) * 64);
        const float4* r1 = (const float4*)(w_dec + (size_t)(obase + 1) * 64);
        const float4* r2 = (const float4*)(w_dec + (size_t)(obase + 2) * 64);
        const float4* r3 = (const float4*)(w_dec + (size_t)(obase + 3) * 64);
        float4 bd = *(const float4*)(b_dec + obase);
        float a0 = bd.x, a1 = bd.y, a2 = bd.z, a3 = bd.w;
#pragma unroll
        for (int q = 0; q < 16; ++q) {
            float4 pv = p4[q];
            float4 v0 = r0[q], v1 = r1[q], v2 = r2[q], v3 = r3[q];
            a0 = fmaf(v0.x, pv.x, a0); a0 = fmaf(v0.y, pv.y, a0);
            a0 = fmaf(v0.z, pv.z, a0); a0 = fmaf(v0.w, pv.w, a0);
            a1 = fmaf(v1.x, pv.x, a1); a1 = fmaf(v1.y, pv.y, a1);
            a1 = fmaf(v1.z, pv.z, a1); a1 = fmaf(v1.w, pv.w, a1);
            a2 = fmaf(v2.x, pv.x, a2); a2 = fmaf(v2.y, pv.y, a2);
            a2 = fmaf(v2.z, pv.z, a2); a2 = fmaf(v2.w, pv.w, a2);
            a3 = fmaf(v3.x, pv.x, a3); a3 = fmaf(v3.y, pv.y, a3);
            a3 = fmaf(v3.z, pv.z, a3); a3 = fmaf(v3.w, pv.w, a3);
        }
        float4 res = make_float4(a0, a1, a2, a3);
        *(float4*)(out + ((size_t)blockIdx.x * 8 + bb) * 128 + obase) = res;
    }
}

extern "C" void kernel_launch(void* const* d_in, const int* in_sizes, int n_in,
                              void* d_out, int out_size, void* d_ws, size_t ws_size,
                              hipStream_t stream)
{
    const float* x    = (const float*)d_in[0];
    const float* w1   = (const float*)d_in[1];
    const float* b1   = (const float*)d_in[2];
    const float* w2   = (const float*)d_in[3];
    const float* b2   = (const float*)d_in[4];
    const float* wihf = (const float*)d_in[5];
    const float* whhf = (const float*)d_in[6];
    const float* bihf = (const float*)d_in[7];
    const float* bhhf = (const float*)d_in[8];
    const float* wihb = (const float*)d_in[9];
    const float* whhb = (const float*)d_in[10];
    const float* bihb = (const float*)d_in[11];
    const float* bhhb = (const float*)d_in[12];
    const float* wdec = (const float*)d_in[13];
    const float* bdec = (const float*)d_in[14];
    float* out = (float*)d_out;
    float* ws  = (float*)d_ws;

    const int B = in_sizes[0] / SEQB;      // 32768
    const int grid = B / 8;                // 8 batch rows per 256-thread block

    hipLaunchKernelGGL(gru_precompute_kernel, dim3(1), dim3(192), 0, stream,
                       wihf, bihf, wihb, bihb, w2, b2, ws);
    hipLaunchKernelGGL(gru_main_kernel, dim3(grid), dim3(256), 0, stream,
                       x, w1, b1, whhf, bhhf, whhb, bhhb, ws, wdec, bdec, out);
}

// Round 2
// 348.546 us; speedup vs baseline: 1.5407x; 1.5407x over previous
//
#include <hip/hip_runtime.h>

// TimeTempTransformerModule: MLP(1->16->32) -> biGRU(H=32, SEQ=32) -> meanpool -> dec(64->128)
// B = 32768 batch rows, all fp32.
//
// Mapping v2: 32-lane group handles TWO batch rows (wave = 4 rows, block = 16 rows).
// Lane j owns hidden unit j for both rows:
//   - registers hold w_hh rows {j, 32+j, 64+j} (96 VGPR) and Wc rows (48 VGPR), shared by both rows
//   - h broadcast via LDS: 1 ds_write_b32 per row + 8 broadcast ds_read_b128 per row per step
//   - h1[16] (post-leakyrelu MLP hidden) precomputed per block into LDS, broadcast reads
// Precompute kernel folds w_ih through the second linear layer:
//   Wc = w_ih @ w2  [96x16],  bc = w_ih @ b2 + b_ih  [96]   (per direction)

#define SEQB 32
#define NH   16   // MLP hidden
#define DH   32   // GRU hidden
#define RPB  16   // batch rows per block

__device__ __forceinline__ float fast_sigmoid(float v) {
    return __builtin_amdgcn_rcpf(1.0f + __expf(-v));
}
__device__ __forceinline__ float fast_tanh(float v) {
    // tanh(v) = 1 - 2/(exp(2v)+1)
    return fmaf(-2.0f, __builtin_amdgcn_rcpf(1.0f + __expf(2.0f * v)), 1.0f);
}

// ws layout (floats): [dir0: Wc 96*16 | bc 96][dir1: Wc 96*16 | bc 96]
#define WS_STRIDE 1632

__global__ __launch_bounds__(192) void gru_precompute_kernel(
    const float* __restrict__ w_ih_f, const float* __restrict__ b_ih_f,
    const float* __restrict__ w_ih_b, const float* __restrict__ b_ih_b,
    const float* __restrict__ w2, const float* __restrict__ b2,
    float* __restrict__ ws)
{
    const int t   = threadIdx.x;
    const int dir = t / 96;
    const int g   = t % 96;
    const float* wih = dir ? w_ih_b : w_ih_f;
    const float* bih = dir ? b_ih_b : b_ih_f;
    float* Wc = ws + dir * WS_STRIDE;
    float* bc = Wc + 96 * NH;

    float acc[NH];
#pragma unroll
    for (int m = 0; m < NH; ++m) acc[m] = 0.0f;
    float accb = bih[g];
    for (int d = 0; d < DH; ++d) {
        float wv = wih[g * DH + d];
        accb = fmaf(wv, b2[d], accb);
#pragma unroll
        for (int m = 0; m < NH; ++m) acc[m] = fmaf(wv, w2[d * NH + m], acc[m]);
    }
#pragma unroll
    for (int m = 0; m < NH; ++m) Wc[g * NH + m] = acc[m];
    bc[g] = accb;
}

#define PSTRIDE 68  // padded pooled-row stride (floats): 68%32=4 -> rp vs rp+1 hit different banks

__global__ __launch_bounds__(256, 2) void gru_main_kernel(
    const float* __restrict__ x,
    const float* __restrict__ w1, const float* __restrict__ b1,
    const float* __restrict__ whh_f, const float* __restrict__ bhh_f,
    const float* __restrict__ whh_b, const float* __restrict__ bhh_b,
    const float* __restrict__ wsbuf,
    const float* __restrict__ w_dec, const float* __restrict__ b_dec,
    float* __restrict__ out)
{
    __shared__ __align__(16) float lds_h1[RPB * SEQB * NH];  // 32 KB
    __shared__ __align__(16) float lds_hb[RPB * DH];         // 2 KB: [row][32]
    __shared__ __align__(16) float lds_p[RPB * PSTRIDE];     // 4.25 KB

    const int tid = threadIdx.x;
    const int j   = tid & 31;   // hidden unit owned by this lane
    const int g   = tid >> 5;   // lane group (0..7); handles rows 2g, 2g+1

    // ---- Phase 1: per-block h1 table. 512 samples, 2 per thread ----
    {
#pragma unroll
        for (int it = 0; it < 2; ++it) {
            const int idx = tid + it * 256;                 // (row = idx>>5, s = idx&31)
            float xs = x[(size_t)blockIdx.x * (RPB * SEQB) + idx]; // coalesced
            float tv[NH];
#pragma unroll
            for (int m = 0; m < NH; ++m) {
                float t = fmaf(xs, w1[m], b1[m]);
                tv[m] = t > 0.0f ? t : 0.01f * t; // leaky_relu(0.01)
            }
            float4* dst = (float4*)&lds_h1[idx * NH];
#pragma unroll
            for (int q = 0; q < 4; ++q)
                dst[q] = make_float4(tv[4*q], tv[4*q+1], tv[4*q+2], tv[4*q+3]);
        }
    }
    __syncthreads();

    const int rA = 2 * g, rB = 2 * g + 1;
    const float* h1A = &lds_h1[rA * (SEQB * NH)];
    const float* h1B = &lds_h1[rB * (SEQB * NH)];
    float* hbA = &lds_hb[rA * DH];
    float* hbB = &lds_hb[rB * DH];

#pragma unroll 1
    for (int dir = 0; dir < 2; ++dir) {
        const float* whh = dir ? whh_b : whh_f;
        const float* bhh = dir ? bhh_b : bhh_f;
        const float* Wc  = wsbuf + dir * WS_STRIDE;
        const float* bc  = Wc + 96 * NH;

        // per-lane weight rows -> registers (shared across both rows)
        float wr[DH], wz[DH], wn[DH];
        {
            const float4* p0 = (const float4*)(whh + (j) * DH);
            const float4* p1 = (const float4*)(whh + (32 + j) * DH);
            const float4* p2 = (const float4*)(whh + (64 + j) * DH);
#pragma unroll
            for (int q = 0; q < 8; ++q) {
                float4 v0 = p0[q]; wr[4*q]=v0.x; wr[4*q+1]=v0.y; wr[4*q+2]=v0.z; wr[4*q+3]=v0.w;
                float4 v1 = p1[q]; wz[4*q]=v1.x; wz[4*q+1]=v1.y; wz[4*q+2]=v1.z; wz[4*q+3]=v1.w;
                float4 v2 = p2[q]; wn[4*q]=v2.x; wn[4*q+1]=v2.y; wn[4*q+2]=v2.z; wn[4*q+3]=v2.w;
            }
        }
        float cr[NH], cz[NH], cn[NH];
        {
            const float4* p0 = (const float4*)(Wc + (j) * NH);
            const float4* p1 = (const float4*)(Wc + (32 + j) * NH);
            const float4* p2 = (const float4*)(Wc + (64 + j) * NH);
#pragma unroll
            for (int q = 0; q < 4; ++q) {
                float4 v0 = p0[q]; cr[4*q]=v0.x; cr[4*q+1]=v0.y; cr[4*q+2]=v0.z; cr[4*q+3]=v0.w;
                float4 v1 = p1[q]; cz[4*q]=v1.x; cz[4*q+1]=v1.y; cz[4*q+2]=v1.z; cz[4*q+3]=v1.w;
                float4 v2 = p2[q]; cn[4*q]=v2.x; cn[4*q+1]=v2.y; cn[4*q+2]=v2.z; cn[4*q+3]=v2.w;
            }
        }
        const float br  = bc[j]      + bhh[j];       // r bias (gx + gh)
        const float bz  = bc[32 + j] + bhh[32 + j];  // z bias
        const float bnx = bc[64 + j];                // n bias, gx part
        const float bnh = bhh[64 + j];               // n bias, gh part (inside r*gh_n)

        float hA = 0.0f, hB = 0.0f, poolA = 0.0f, poolB = 0.0f;
        hbA[j] = 0.0f;   // reset h broadcast buffer (own-group only, same wave)
        hbB[j] = 0.0f;

#pragma unroll 1
        for (int ss = 0; ss < SEQB; ++ss) {
            const int s = dir ? (SEQB - 1 - ss) : ss;

            // ---- gx (folded through Wc), quad-at-a-time, both rows ----
            float arA = br, azA = bz, anA = bnx;
            float arB = br, azB = bz, anB = bnx;
            {
                const float4* qA = (const float4*)(h1A + s * NH);
                const float4* qB = (const float4*)(h1B + s * NH);
#pragma unroll
                for (int q = 0; q < 4; ++q) {
                    float4 va = qA[q], vb = qB[q];
                    arA = fmaf(cr[4*q+0], va.x, arA); arA = fmaf(cr[4*q+1], va.y, arA);
                    arA = fmaf(cr[4*q+2], va.z, arA); arA = fmaf(cr[4*q+3], va.w, arA);
                    azA = fmaf(cz[4*q+0], va.x, azA); azA = fmaf(cz[4*q+1], va.y, azA);
                    azA = fmaf(cz[4*q+2], va.z, azA); azA = fmaf(cz[4*q+3], va.w, azA);
                    anA = fmaf(cn[4*q+0], va.x, anA); anA = fmaf(cn[4*q+1], va.y, anA);
                    anA = fmaf(cn[4*q+2], va.z, anA); anA = fmaf(cn[4*q+3], va.w, anA);
                    arB = fmaf(cr[4*q+0], vb.x, arB); arB = fmaf(cr[4*q+1], vb.y, arB);
                    arB = fmaf(cr[4*q+2], vb.z, arB); arB = fmaf(cr[4*q+3], vb.w, arB);
                    azB = fmaf(cz[4*q+0], vb.x, azB); azB = fmaf(cz[4*q+1], vb.y, azB);
                    azB = fmaf(cz[4*q+2], vb.z, azB); azB = fmaf(cz[4*q+3], vb.w, azB);
                    anB = fmaf(cn[4*q+0], vb.x, anB); anB = fmaf(cn[4*q+1], vb.y, anB);
                    anB = fmaf(cn[4*q+2], vb.z, anB); anB = fmaf(cn[4*q+3], vb.w, anB);
                }
            }

            // ---- gh: broadcast reads of previous h vectors, quad-at-a-time ----
            float grA = 0.0f, gzA = 0.0f, gnA = bnh;
            float grB = 0.0f, gzB = 0.0f, gnB = bnh;
            {
                const float4* qA = (const float4*)hbA;
                const float4* qB = (const float4*)hbB;
#pragma unroll
                for (int q = 0; q < 8; ++q) {
                    float4 va = qA[q], vb = qB[q];
                    grA = fmaf(wr[4*q+0], va.x, grA); grA = fmaf(wr[4*q+1], va.y, grA);
                    grA = fmaf(wr[4*q+2], va.z, grA); grA = fmaf(wr[4*q+3], va.w, grA);
                    gzA = fmaf(wz[4*q+0], va.x, gzA); gzA = fmaf(wz[4*q+1], va.y, gzA);
                    gzA = fmaf(wz[4*q+2], va.z, gzA); gzA = fmaf(wz[4*q+3], va.w, gzA);
                    gnA = fmaf(wn[4*q+0], va.x, gnA); gnA = fmaf(wn[4*q+1], va.y, gnA);
                    gnA = fmaf(wn[4*q+2], va.z, gnA); gnA = fmaf(wn[4*q+3], va.w, gnA);
                    grB = fmaf(wr[4*q+0], vb.x, grB); grB = fmaf(wr[4*q+1], vb.y, grB);
                    grB = fmaf(wr[4*q+2], vb.z, grB); grB = fmaf(wr[4*q+3], vb.w, grB);
                    gzB = fmaf(wz[4*q+0], vb.x, gzB); gzB = fmaf(wz[4*q+1], vb.y, gzB);
                    gzB = fmaf(wz[4*q+2], vb.z, gzB); gzB = fmaf(wz[4*q+3], vb.w, gzB);
                    gnB = fmaf(wn[4*q+0], vb.x, gnB); gnB = fmaf(wn[4*q+1], vb.y, gnB);
                    gnB = fmaf(wn[4*q+2], vb.z, gnB); gnB = fmaf(wn[4*q+3], vb.w, gnB);
                }
            }

            // ---- activations + state update, both rows ----
            float rA_ = fast_sigmoid(arA + grA);
            float zA_ = fast_sigmoid(azA + gzA);
            float nA_ = fast_tanh(fmaf(rA_, gnA, anA));
            hA = fmaf(zA_, hA - nA_, nA_);
            poolA += hA;

            float rB_ = fast_sigmoid(arB + grB);
            float zB_ = fast_sigmoid(azB + gzB);
            float nB_ = fast_tanh(fmaf(rB_, gnB, anB));
            hB = fmaf(zB_, hB - nB_, nB_);
            poolB += hB;

            // publish new h for next step (same wave; DS pipe is in-order)
            hbA[j] = hA;
            hbB[j] = hB;
        }

        // store pooled halves (padded rows)
        const int off = dir ? 32 : 0;
        lds_p[rA * PSTRIDE + off + j] = poolA * (1.0f / 32.0f);
        lds_p[rB * PSTRIDE + off + j] = poolB * (1.0f / 32.0f);
    }

    __syncthreads();

    // ---- Decoder: pooled[64] @ w_dec.T + b_dec ; 16 rows, 128 outputs ----
    {
        const int o4 = (tid & 31) * 4;   // 4 outputs per thread
        const int rp = tid >> 5;         // rows rp and rp+8
        const float4* pPA = (const float4*)&lds_p[rp * PSTRIDE];
        const float4* pPB = (const float4*)&lds_p[(rp + 8) * PSTRIDE];
        const float4* r0 = (const float4*)(w_dec + (size_t)(o4 + 0) * 64);
        const float4* r1 = (const float4*)(w_dec + (size_t)(o4 + 1) * 64);
        const float4* r2 = (const float4*)(w_dec + (size_t)(o4 + 2) * 64);
        const float4* r3 = (const float4*)(w_dec + (size_t)(o4 + 3) * 64);
        float4 bd = *(const float4*)(b_dec + o4);
        float a0 = bd.x, a1 = bd.y, a2 = bd.z, a3 = bd.w;
        float c0 = bd.x, c1 = bd.y, c2 = bd.z, c3 = bd.w;
#pragma unroll
        for (int q = 0; q < 16; ++q) {
            float4 pa = pPA[q], pb = pPB[q];
            float4 v0 = r0[q], v1 = r1[q], v2 = r2[q], v3 = r3[q];
            a0 = fmaf(v0.x, pa.x, a0); a0 = fmaf(v0.y, pa.y, a0);
            a0 = fmaf(v0.z, pa.z, a0); a0 = fmaf(v0.w, pa.w, a0);
            a1 = fmaf(v1.x, pa.x, a1); a1 = fmaf(v1.y, pa.y, a1);
            a1 = fmaf(v1.z, pa.z, a1); a1 = fmaf(v1.w, pa.w, a1);
            a2 = fmaf(v2.x, pa.x, a2); a2 = fmaf(v2.y, pa.y, a2);
            a2 = fmaf(v2.z, pa.z, a2); a2 = fmaf(v2.w, pa.w, a2);
            a3 = fmaf(v3.x, pa.x, a3); a3 = fmaf(v3.y, pa.y, a3);
            a3 = fmaf(v3.z, pa.z, a3); a3 = fmaf(v3.w, pa.w, a3);
            c0 = fmaf(v0.x, pb.x, c0); c0 = fmaf(v0.y, pb.y, c0);
            c0 = fmaf(v0.z, pb.z, c0); c0 = fmaf(v0.w, pb.w, c0);
            c1 = fmaf(v1.x, pb.x, c1); c1 = fmaf(v1.y, pb.y, c1);
            c1 = fmaf(v1.z, pb.z, c1); c1 = fmaf(v1.w, pb.w, c1);
            c2 = fmaf(v2.x, pb.x, c2); c2 = fmaf(v2.y, pb.y, c2);
            c2 = fmaf(v2.z, pb.z, c2); c2 = fmaf(v2.w, pb.w, c2);
            c3 = fmaf(v3.x, pb.x, c3); c3 = fmaf(v3.y, pb.y, c3);
            c3 = fmaf(v3.z, pb.z, c3); c3 = fmaf(v3.w, pb.w, c3);
        }
        float* obaseA = out + ((size_t)blockIdx.x * RPB + rp) * 128 + o4;
        float* obaseB = out + ((size_t)blockIdx.x * RPB + rp + 8) * 128 + o4;
        *(float4*)obaseA = make_float4(a0, a1, a2, a3);
        *(float4*)obaseB = make_float4(c0, c1, c2, c3);
    }
}

extern "C" void kernel_launch(void* const* d_in, const int* in_sizes, int n_in,
                              void* d_out, int out_size, void* d_ws, size_t ws_size,
                              hipStream_t stream)
{
    const float* x    = (const float*)d_in[0];
    const float* w1   = (const float*)d_in[1];
    const float* b1   = (const float*)d_in[2];
    const float* w2   = (const float*)d_in[3];
    const float* b2   = (const float*)d_in[4];
    const float* wihf = (const float*)d_in[5];
    const float* whhf = (const float*)d_in[6];
    const float* bihf = (const float*)d_in[7];
    const float* bhhf = (const float*)d_in[8];
    const float* wihb = (const float*)d_in[9];
    const float* whhb = (const float*)d_in[10];
    const float* bihb = (const float*)d_in[11];
    const float* bhhb = (const float*)d_in[12];
    const float* wdec = (const float*)d_in[13];
    const float* bdec = (const float*)d_in[14];
    float* out = (float*)d_out;
    float* ws  = (float*)d_ws;

    const int B = in_sizes[0] / SEQB;      // 32768
    const int grid = B / RPB;              // 16 batch rows per 256-thread block

    hipLaunchKernelGGL(gru_precompute_kernel, dim3(1), dim3(192), 0, stream,
                       wihf, bihf, wihb, bihb, w2, b2, ws);
    hipLaunchKernelGGL(gru_main_kernel, dim3(grid), dim3(256), 0, stream,
                       x, w1, b1, whhf, bhhf, whhb, bhhb, ws, wdec, bdec, out);
}

// Round 3
// 98.152 us; speedup vs baseline: 5.4710x; 3.5511x over previous
//
#include <hip/hip_runtime.h>

// TimeTempTransformerModule: MLP(1->16->32) -> biGRU(H=32, SEQ=32) -> meanpool -> dec(64->128)
// B = 32768 rows, fp32 in/out.
//
// v3: MFMA recurrence. One wave (64 thr) = 16 batch rows, no barriers.
//   gh = h[16x32] @ whh^T  : 6 tiles x mfma_f32_16x16x32_bf16, bf16 hi/lo split (3-term)
//   gx = h1[16x16] @ Wc^T  : same intrinsic, B zero-padded for k>=16, single bf16
//   decoder pooled[16x64] @ w_dec^T : 8 tiles x 2 k-chunks, pooled hi/lo split
// h round-trips step-to-step through LDS h_mat[16][33] fp32 (pad 33: 2-way, free).
// h1 A-frags precomputed per wave into LDS (16KB), read as ds_read_b128 per step.
// Precompute kernel folds Wc = w_ih@w2, bc = w_ih@b2 + b_ih and emits all B-frags
// in MFMA lane order: A/B lane=idx%16, k=8*(lane/16)+e ; D: n=lane&15, m=4*(lane>>4)+reg.

#define SEQB 32
#define NH   16
#define DH   32

typedef __attribute__((ext_vector_type(4))) float f32x4;
typedef __attribute__((ext_vector_type(8))) short s16x8;
typedef __attribute__((ext_vector_type(4))) unsigned int u32x4;

#define MFMA_B16(a, b, c) __builtin_amdgcn_mfma_f32_16x16x32_bf16((a), (b), (c), 0, 0, 0)

// ws layout (bytes)
#define OFF_BGH_HI 0u        // [dir][t<6][lane<64] 16B
#define OFF_BGH_LO 12288u
#define OFF_BGX    24576u    // [dir][t<6][lane] 16B (k>=16 zeroed)
#define OFF_BDEC   36864u    // [kc<2][t<8][lane] 16B
#define OFF_BC     53248u    // [dir][96] f32
#define OFF_WC     54016u    // [dir][96][16] f32 temp

__device__ __forceinline__ unsigned short bf16_rne(float x) {
    unsigned u = __float_as_uint(x);
    return (unsigned short)((u + 0x7fffu + ((u >> 16) & 1u)) >> 16);
}

// Load 8 consecutive fp32, produce bf16 hi (trunc) and lo (residual, trunc) packed frags.
__device__ __forceinline__ void split_pack8(const float* s8, s16x8& hi, s16x8& lo) {
    float f[8];
#pragma unroll
    for (int e = 0; e < 8; ++e) f[e] = s8[e];
    unsigned ub[8];
#pragma unroll
    for (int e = 0; e < 8; ++e) ub[e] = __float_as_uint(f[e]);
    float lf[8];
#pragma unroll
    for (int e = 0; e < 8; ++e) lf[e] = f[e] - __uint_as_float(ub[e] & 0xffff0000u);
    u32x4 ph, pl;
    ph.x = (ub[1] & 0xffff0000u) | (ub[0] >> 16);
    ph.y = (ub[3] & 0xffff0000u) | (ub[2] >> 16);
    ph.z = (ub[5] & 0xffff0000u) | (ub[4] >> 16);
    ph.w = (ub[7] & 0xffff0000u) | (ub[6] >> 16);
    pl.x = (__float_as_uint(lf[1]) & 0xffff0000u) | (__float_as_uint(lf[0]) >> 16);
    pl.y = (__float_as_uint(lf[3]) & 0xffff0000u) | (__float_as_uint(lf[2]) >> 16);
    pl.z = (__float_as_uint(lf[5]) & 0xffff0000u) | (__float_as_uint(lf[4]) >> 16);
    pl.w = (__float_as_uint(lf[7]) & 0xffff0000u) | (__float_as_uint(lf[6]) >> 16);
    hi = __builtin_bit_cast(s16x8, ph);
    lo = __builtin_bit_cast(s16x8, pl);
}

__global__ __launch_bounds__(1024) void gru_precompute_kernel(
    const float* __restrict__ w_ih_f, const float* __restrict__ b_ih_f,
    const float* __restrict__ w_ih_b, const float* __restrict__ b_ih_b,
    const float* __restrict__ w2, const float* __restrict__ b2,
    const float* __restrict__ whh_f, const float* __restrict__ whh_b,
    const float* __restrict__ w_dec,
    unsigned char* __restrict__ ws)
{
    const int t = threadIdx.x;
    float* WC = (float*)(ws + OFF_WC);
    float* BC = (float*)(ws + OFF_BC);

    if (t < 192) {  // Wc = w_ih@w2 [96x16], bc = w_ih@b2 + b_ih
        const int dir = t / 96, g = t % 96;
        const float* wih = dir ? w_ih_b : w_ih_f;
        const float* bih = dir ? b_ih_b : b_ih_f;
        float acc[NH];
#pragma unroll
        for (int m = 0; m < NH; ++m) acc[m] = 0.0f;
        float ab = bih[g];
        for (int d = 0; d < DH; ++d) {
            float wv = wih[g * DH + d];
            ab = fmaf(wv, b2[d], ab);
#pragma unroll
            for (int m = 0; m < NH; ++m) acc[m] = fmaf(wv, w2[d * NH + m], acc[m]);
        }
#pragma unroll
        for (int m = 0; m < NH; ++m) WC[(dir * 96 + g) * NH + m] = acc[m];
        BC[dir * 96 + g] = ab;
    }
    __syncthreads();

    if (t < 768) {  // gh B-frags (hi/lo split) + gx B-frags (single, k>=16 zero)
        const int dir = t / 384, r = t % 384, tt = r / 64, lane = r % 64;
        const int gate = tt * 16 + (lane & 15);
        const int kb = (lane >> 4) * 8;
        const float* whh = dir ? whh_b : whh_f;
        unsigned short* dh = (unsigned short*)(ws + OFF_BGH_HI + dir * 6144u + tt * 1024u + lane * 16u);
        unsigned short* dl = (unsigned short*)(ws + OFF_BGH_LO + dir * 6144u + tt * 1024u + lane * 16u);
        unsigned short* dx = (unsigned short*)(ws + OFF_BGX    + dir * 6144u + tt * 1024u + lane * 16u);
#pragma unroll
        for (int e = 0; e < 8; ++e) {
            float v = whh[gate * DH + kb + e];
            unsigned ub = __float_as_uint(v);
            dh[e] = (unsigned short)(ub >> 16);
            dl[e] = bf16_rne(v - __uint_as_float(ub & 0xffff0000u));
            int k = kb + e;
            float vx = (k < NH) ? WC[(dir * 96 + gate) * NH + k] : 0.0f;
            dx[e] = bf16_rne(vx);
        }
    }
    {  // decoder B-frags: B[k][n] = w_dec[n][k], n=16t+(lane&15), k=32kc+8*(lane>>4)+e
        const int kc = t / 512, r = t % 512, tt = r / 64, lane = r % 64;
        const int nn = tt * 16 + (lane & 15);
        const int kb = kc * 32 + (lane >> 4) * 8;
        unsigned short* dd = (unsigned short*)(ws + OFF_BDEC + kc * 8192u + tt * 1024u + lane * 16u);
#pragma unroll
        for (int e = 0; e < 8; ++e) dd[e] = bf16_rne(w_dec[nn * 64 + kb + e]);
    }
}

__global__ __launch_bounds__(64, 2) void gru_mfma_kernel(
    const float* __restrict__ x,
    const float* __restrict__ w1, const float* __restrict__ b1,
    const float* __restrict__ bhh_f, const float* __restrict__ bhh_b,
    const unsigned char* __restrict__ ws,
    const float* __restrict__ b_dec,
    float* __restrict__ out)
{
    __shared__ __align__(16) unsigned char smem[18496];
    float* h_mat  = (float*)(smem + 16384);  // [16][33] fp32, pad-33 (2-way = free)
    float* pooled = (float*)smem;            // [16][65] fp32 overlay (after step loops)

    const int l = threadIdx.x;
    const int n = l & 15;        // MFMA n / A-row m
    const int q = l >> 4;        // k-chunk / D row-quad
    const int j = l & 31;
    const int rowbase = blockIdx.x * 16;

    // ---- Phase 1: h1 A-frags into LDS: [s][j<32] 16B, elem e -> h1[row j&15][mh=8*(j>>4)+e]
    {
        const int sh = l >> 5;  // s-half this lane produces
        const float* xr = x + (size_t)(rowbase + n) * SEQB + sh * 16;
        float xs[16];
        {
            const float4* xp = (const float4*)xr;
            float4 a = xp[0], b = xp[1], c = xp[2], d = xp[3];
            xs[0]=a.x; xs[1]=a.y; xs[2]=a.z; xs[3]=a.w;
            xs[4]=b.x; xs[5]=b.y; xs[6]=b.z; xs[7]=b.w;
            xs[8]=c.x; xs[9]=c.y; xs[10]=c.z; xs[11]=c.w;
            xs[12]=d.x; xs[13]=d.y; xs[14]=d.z; xs[15]=d.w;
        }
        const int mhb = (j >> 4) * 8;
        float w1v[8], b1v[8];
        {
            float4 wa = *(const float4*)(w1 + mhb), wb = *(const float4*)(w1 + mhb + 4);
            float4 ba = *(const float4*)(b1 + mhb), bb = *(const float4*)(b1 + mhb + 4);
            w1v[0]=wa.x; w1v[1]=wa.y; w1v[2]=wa.z; w1v[3]=wa.w;
            w1v[4]=wb.x; w1v[5]=wb.y; w1v[6]=wb.z; w1v[7]=wb.w;
            b1v[0]=ba.x; b1v[1]=ba.y; b1v[2]=ba.z; b1v[3]=ba.w;
            b1v[4]=bb.x; b1v[5]=bb.y; b1v[6]=bb.z; b1v[7]=bb.w;
        }
#pragma unroll
        for (int i = 0; i < 16; ++i) {
            const int s = sh * 16 + i;
            float v[8];
#pragma unroll
            for (int e = 0; e < 8; ++e) {
                float tv = fmaf(xs[i], w1v[e], b1v[e]);
                v[e] = fmaxf(tv, 0.01f * tv);  // leaky_relu
            }
            u32x4 p;
            p.x = (__float_as_uint(v[1]) & 0xffff0000u) | (__float_as_uint(v[0]) >> 16);
            p.y = (__float_as_uint(v[3]) & 0xffff0000u) | (__float_as_uint(v[2]) >> 16);
            p.z = (__float_as_uint(v[5]) & 0xffff0000u) | (__float_as_uint(v[4]) >> 16);
            p.w = (__float_as_uint(v[7]) & 0xffff0000u) | (__float_as_uint(v[6]) >> 16);
            *(u32x4*)(smem + s * 512 + j * 16) = p;
        }
    }

    float pfA[4], pfB[4], pbA[4], pbB[4];
    const f32x4 kz = {0.0f, 0.0f, 0.0f, 0.0f};
    const float* hrd = h_mat + n * 33 + q * 8;   // A-frag read base
    float* hwr = h_mat + (q * 4) * 33 + n;       // D write base

#pragma unroll 1
    for (int dir = 0; dir < 2; ++dir) {
        for (int k2 = l; k2 < 528; k2 += 64) h_mat[k2] = 0.0f;  // h0 = 0

        const float* bhh = dir ? bhh_b : bhh_f;
        const float* bcp = (const float*)(ws + OFF_BC) + dir * 96;
        const unsigned char* phi = ws + OFF_BGH_HI + dir * 6144u + l * 16u;
        const unsigned char* plo = ws + OFF_BGH_LO + dir * 6144u + l * 16u;
        const unsigned char* pgx = ws + OFF_BGX    + dir * 6144u + l * 16u;
        s16x8 Bhi[6], Blo[6], Bx[6];
#pragma unroll
        for (int t = 0; t < 6; ++t) {
            Bhi[t] = *(const s16x8*)(phi + t * 1024);
            Blo[t] = *(const s16x8*)(plo + t * 1024);
            Bx[t]  = *(const s16x8*)(pgx + t * 1024);
        }
        const float nbrA = -(bcp[n]      + bhh[n]);
        const float nbrB = -(bcp[16 + n] + bhh[16 + n]);
        const float nbzA = -(bcp[32 + n] + bhh[32 + n]);
        const float nbzB = -(bcp[48 + n] + bhh[48 + n]);
        const float bcnA = bcp[64 + n], bcnB = bcp[80 + n];
        const float bhnA = bhh[64 + n], bhnB = bhh[80 + n];

        float hA[4] = {0, 0, 0, 0}, hB[4] = {0, 0, 0, 0};
        float pA[4] = {0, 0, 0, 0}, pB[4] = {0, 0, 0, 0};
        const int smask = dir ? 31 : 0;

#pragma unroll 1
        for (int ss = 0; ss < SEQB; ++ss) {
            const int s = ss ^ smask;
            s16x8 ax = *(const s16x8*)(smem + s * 512 + j * 16);  // h1 frag (k>=16 dead via B=0)
            s16x8 ahi, alo;
            split_pack8(hrd, ahi, alo);

            // r,z tiles: gx + gh(split) chained, one acc each
            f32x4 a0 = MFMA_B16(ax, Bx[0], kz);
            a0 = MFMA_B16(alo, Bhi[0], a0); a0 = MFMA_B16(ahi, Blo[0], a0); a0 = MFMA_B16(ahi, Bhi[0], a0);
            f32x4 a1 = MFMA_B16(ax, Bx[1], kz);
            a1 = MFMA_B16(alo, Bhi[1], a1); a1 = MFMA_B16(ahi, Blo[1], a1); a1 = MFMA_B16(ahi, Bhi[1], a1);
            f32x4 a2 = MFMA_B16(ax, Bx[2], kz);
            a2 = MFMA_B16(alo, Bhi[2], a2); a2 = MFMA_B16(ahi, Blo[2], a2); a2 = MFMA_B16(ahi, Bhi[2], a2);
            f32x4 a3 = MFMA_B16(ax, Bx[3], kz);
            a3 = MFMA_B16(alo, Bhi[3], a3); a3 = MFMA_B16(ahi, Blo[3], a3); a3 = MFMA_B16(ahi, Bhi[3], a3);
            // n tiles: gx and gh kept separate (r gates gh)
            f32x4 x4 = MFMA_B16(ax, Bx[4], kz);
            f32x4 x5 = MFMA_B16(ax, Bx[5], kz);
            f32x4 g4 = MFMA_B16(alo, Bhi[4], kz);
            g4 = MFMA_B16(ahi, Blo[4], g4); g4 = MFMA_B16(ahi, Bhi[4], g4);
            f32x4 g5 = MFMA_B16(alo, Bhi[5], kz);
            g5 = MFMA_B16(ahi, Blo[5], g5); g5 = MFMA_B16(ahi, Bhi[5], g5);

#pragma unroll
            for (int rg = 0; rg < 4; ++rg) {
                float rA = __builtin_amdgcn_rcpf(1.0f + __expf(nbrA - a0[rg]));
                float zA = __builtin_amdgcn_rcpf(1.0f + __expf(nbzA - a2[rg]));
                float tA = fmaf(rA, g4[rg] + bhnA, x4[rg] + bcnA);
                float nA = fmaf(-2.0f, __builtin_amdgcn_rcpf(1.0f + __expf(tA + tA)), 1.0f);
                hA[rg] = fmaf(zA, hA[rg] - nA, nA);
                pA[rg] += hA[rg];

                float rB = __builtin_amdgcn_rcpf(1.0f + __expf(nbrB - a1[rg]));
                float zB = __builtin_amdgcn_rcpf(1.0f + __expf(nbzB - a3[rg]));
                float tB = fmaf(rB, g5[rg] + bhnB, x5[rg] + bcnB);
                float nB = fmaf(-2.0f, __builtin_amdgcn_rcpf(1.0f + __expf(tB + tB)), 1.0f);
                hB[rg] = fmaf(zB, hB[rg] - nB, nB);
                pB[rg] += hB[rg];

                hwr[rg * 33]      = hA[rg];
                hwr[rg * 33 + 16] = hB[rg];
            }
        }
        if (dir == 0) {
#pragma unroll
            for (int rg = 0; rg < 4; ++rg) { pfA[rg] = pA[rg]; pfB[rg] = pB[rg]; }
        } else {
#pragma unroll
            for (int rg = 0; rg < 4; ++rg) { pbA[rg] = pA[rg]; pbB[rg] = pB[rg]; }
        }
    }

    // ---- pooled [16][65] (overlays dead h1 frags), cols: [fwd 0..31 | bwd 32..63]
#pragma unroll
    for (int rg = 0; rg < 4; ++rg) {
        const int m = q * 4 + rg;
        pooled[m * 65 + n]      = pfA[rg] * 0.03125f;
        pooled[m * 65 + 16 + n] = pfB[rg] * 0.03125f;
        pooled[m * 65 + 32 + n] = pbA[rg] * 0.03125f;
        pooled[m * 65 + 48 + n] = pbB[rg] * 0.03125f;
    }

    // ---- decoder: out[16x128] = pooled @ w_dec^T + b_dec (pooled hi/lo split)
    {
        const float* prd = pooled + n * 65 + q * 8;
        s16x8 aQ0hi, aQ0lo, aQ1hi, aQ1lo;
        split_pack8(prd, aQ0hi, aQ0lo);
        split_pack8(prd + 32, aQ1hi, aQ1lo);
#pragma unroll
        for (int t = 0; t < 8; ++t) {
            s16x8 bd0 = *(const s16x8*)(ws + OFF_BDEC + t * 1024u + l * 16u);
            s16x8 bd1 = *(const s16x8*)(ws + OFF_BDEC + 8192u + t * 1024u + l * 16u);
            float bdv = b_dec[t * 16 + n];
            f32x4 acc = {bdv, bdv, bdv, bdv};
            acc = MFMA_B16(aQ0lo, bd0, acc);
            acc = MFMA_B16(aQ1lo, bd1, acc);
            acc = MFMA_B16(aQ0hi, bd0, acc);
            acc = MFMA_B16(aQ1hi, bd1, acc);
#pragma unroll
            for (int rg = 0; rg < 4; ++rg)
                out[(size_t)(rowbase + q * 4 + rg) * 128 + t * 16 + n] = acc[rg];
        }
    }
}

extern "C" void kernel_launch(void* const* d_in, const int* in_sizes, int n_in,
                              void* d_out, int out_size, void* d_ws, size_t ws_size,
                              hipStream_t stream)
{
    const float* x    = (const float*)d_in[0];
    const float* w1   = (const float*)d_in[1];
    const float* b1   = (const float*)d_in[2];
    const float* w2   = (const float*)d_in[3];
    const float* b2   = (const float*)d_in[4];
    const float* wihf = (const float*)d_in[5];
    const float* whhf = (const float*)d_in[6];
    const float* bihf = (const float*)d_in[7];
    const float* bhhf = (const float*)d_in[8];
    const float* wihb = (const float*)d_in[9];
    const float* whhb = (const float*)d_in[10];
    const float* bihb = (const float*)d_in[11];
    const float* bhhb = (const float*)d_in[12];
    const float* wdec = (const float*)d_in[13];
    const float* bdec = (const float*)d_in[14];
    float* out = (float*)d_out;
    unsigned char* ws = (unsigned char*)d_ws;

    const int B = in_sizes[0] / SEQB;  // 32768
    const int grid = B / 16;           // 16 rows per 64-thread (1-wave) block

    hipLaunchKernelGGL(gru_precompute_kernel, dim3(1), dim3(1024), 0, stream,
                       wihf, bihf, wihb, bihb, w2, b2, whhf, whhb, wdec, ws);
    hipLaunchKernelGGL(gru_mfma_kernel, dim3(grid), dim3(64), 0, stream,
                       x, w1, b1, bhhf, bhhb, ws, bdec, out);
}

// Round 4
// 92.783 us; speedup vs baseline: 5.7876x; 1.0579x over previous
//
#include <hip/hip_runtime.h>

// TimeTempTransformerModule: MLP(1->16->32) -> biGRU(H=32, SEQ=32) -> meanpool -> dec(64->128)
// B = 32768 rows, fp32 in/out.
//
// v4 = v3 (MFMA recurrence, 1 wave = 16 rows, no barriers) +
//   - B-fragments PINNED in VGPRs via empty asm (compiler was re-loading all 18
//     frags from global ws every step -> ~1300 cy/step of L2 latency; VGPR was 88)
//   - h_mat stride 33->36, pooled 65->68: 16B-aligned -> ds_read_b128 for h/pooled
//   - split_pack8 via v_perm_b32 (1 op per bf16-pair pack)

#define SEQB 32
#define NH   16
#define DH   32

typedef __attribute__((ext_vector_type(4))) float f32x4;
typedef __attribute__((ext_vector_type(8))) short s16x8;
typedef __attribute__((ext_vector_type(4))) unsigned int u32x4;

#define MFMA_B16(a, b, c) __builtin_amdgcn_mfma_f32_16x16x32_bf16((a), (b), (c), 0, 0, 0)

// ws layout (bytes)
#define OFF_BGH_HI 0u        // [dir][t<6][lane<64] 16B
#define OFF_BGH_LO 12288u
#define OFF_BGX    24576u    // [dir][t<6][lane] 16B (k>=16 zeroed)
#define OFF_BDEC   36864u    // [kc<2][t<8][lane] 16B
#define OFF_BC     53248u    // [dir][96] f32
#define OFF_WC     54016u    // [dir][96][16] f32 temp

#define HSTR 36              // h_mat row stride (floats): 16B-aligned, 2-way banks (free)
#define PSTR 68              // pooled row stride (floats): 16B-aligned

__device__ __forceinline__ unsigned short bf16_rne(float x) {
    unsigned u = __float_as_uint(x);
    return (unsigned short)((u + 0x7fffu + ((u >> 16) & 1u)) >> 16);
}

// hi16(a)<<16 | hi16(b) : result = (a & 0xffff0000) | (b >> 16)
__device__ __forceinline__ unsigned pack_hi(unsigned a, unsigned b) {
    return __builtin_amdgcn_perm(a, b, 0x07060302u);
}

// Load 8 consecutive aligned fp32, produce bf16 hi (trunc) + lo (residual, trunc) frags.
__device__ __forceinline__ void split_pack8(const float* s8, s16x8& hi, s16x8& lo) {
    float4 fa = *(const float4*)s8;
    float4 fb = *(const float4*)(s8 + 4);
    unsigned ub[8] = {__float_as_uint(fa.x), __float_as_uint(fa.y),
                      __float_as_uint(fa.z), __float_as_uint(fa.w),
                      __float_as_uint(fb.x), __float_as_uint(fb.y),
                      __float_as_uint(fb.z), __float_as_uint(fb.w)};
    float f[8] = {fa.x, fa.y, fa.z, fa.w, fb.x, fb.y, fb.z, fb.w};
    unsigned lb[8];
#pragma unroll
    for (int e = 0; e < 8; ++e)
        lb[e] = __float_as_uint(f[e] - __uint_as_float(ub[e] & 0xffff0000u));
    u32x4 ph, pl;
    ph.x = pack_hi(ub[1], ub[0]); ph.y = pack_hi(ub[3], ub[2]);
    ph.z = pack_hi(ub[5], ub[4]); ph.w = pack_hi(ub[7], ub[6]);
    pl.x = pack_hi(lb[1], lb[0]); pl.y = pack_hi(lb[3], lb[2]);
    pl.z = pack_hi(lb[5], lb[4]); pl.w = pack_hi(lb[7], lb[6]);
    hi = __builtin_bit_cast(s16x8, ph);
    lo = __builtin_bit_cast(s16x8, pl);
}

__global__ __launch_bounds__(1024) void gru_precompute_kernel(
    const float* __restrict__ w_ih_f, const float* __restrict__ b_ih_f,
    const float* __restrict__ w_ih_b, const float* __restrict__ b_ih_b,
    const float* __restrict__ w2, const float* __restrict__ b2,
    const float* __restrict__ whh_f, const float* __restrict__ whh_b,
    const float* __restrict__ w_dec,
    unsigned char* __restrict__ ws)
{
    const int t = threadIdx.x;
    float* WC = (float*)(ws + OFF_WC);
    float* BC = (float*)(ws + OFF_BC);

    if (t < 192) {  // Wc = w_ih@w2 [96x16], bc = w_ih@b2 + b_ih
        const int dir = t / 96, g = t % 96;
        const float* wih = dir ? w_ih_b : w_ih_f;
        const float* bih = dir ? b_ih_b : b_ih_f;
        float acc[NH];
#pragma unroll
        for (int m = 0; m < NH; ++m) acc[m] = 0.0f;
        float ab = bih[g];
        for (int d = 0; d < DH; ++d) {
            float wv = wih[g * DH + d];
            ab = fmaf(wv, b2[d], ab);
#pragma unroll
            for (int m = 0; m < NH; ++m) acc[m] = fmaf(wv, w2[d * NH + m], acc[m]);
        }
#pragma unroll
        for (int m = 0; m < NH; ++m) WC[(dir * 96 + g) * NH + m] = acc[m];
        BC[dir * 96 + g] = ab;
    }
    __syncthreads();

    if (t < 768) {  // gh B-frags (hi/lo split) + gx B-frags (single, k>=16 zero)
        const int dir = t / 384, r = t % 384, tt = r / 64, lane = r % 64;
        const int gate = tt * 16 + (lane & 15);
        const int kb = (lane >> 4) * 8;
        const float* whh = dir ? whh_b : whh_f;
        unsigned short* dh = (unsigned short*)(ws + OFF_BGH_HI + dir * 6144u + tt * 1024u + lane * 16u);
        unsigned short* dl = (unsigned short*)(ws + OFF_BGH_LO + dir * 6144u + tt * 1024u + lane * 16u);
        unsigned short* dx = (unsigned short*)(ws + OFF_BGX    + dir * 6144u + tt * 1024u + lane * 16u);
#pragma unroll
        for (int e = 0; e < 8; ++e) {
            float v = whh[gate * DH + kb + e];
            unsigned ub = __float_as_uint(v);
            dh[e] = (unsigned short)(ub >> 16);
            dl[e] = bf16_rne(v - __uint_as_float(ub & 0xffff0000u));
            int k = kb + e;
            float vx = (k < NH) ? WC[(dir * 96 + gate) * NH + k] : 0.0f;
            dx[e] = bf16_rne(vx);
        }
    }
    {  // decoder B-frags: B[k][n] = w_dec[n][k], n=16t+(lane&15), k=32kc+8*(lane>>4)+e
        const int kc = t / 512, r = t % 512, tt = r / 64, lane = r % 64;
        const int nn = tt * 16 + (lane & 15);
        const int kb = kc * 32 + (lane >> 4) * 8;
        unsigned short* dd = (unsigned short*)(ws + OFF_BDEC + kc * 8192u + tt * 1024u + lane * 16u);
#pragma unroll
        for (int e = 0; e < 8; ++e) dd[e] = bf16_rne(w_dec[nn * 64 + kb + e]);
    }
}

__global__ __launch_bounds__(64, 2) void gru_mfma_kernel(
    const float* __restrict__ x,
    const float* __restrict__ w1, const float* __restrict__ b1,
    const float* __restrict__ bhh_f, const float* __restrict__ bhh_b,
    const unsigned char* __restrict__ ws,
    const float* __restrict__ b_dec,
    float* __restrict__ out)
{
    __shared__ __align__(16) unsigned char smem[16384 + 16 * HSTR * 4];
    float* h_mat  = (float*)(smem + 16384);  // [16][HSTR] fp32
    float* pooled = (float*)smem;            // [16][PSTR] fp32 overlay (after step loops)

    const int l = threadIdx.x;
    const int n = l & 15;        // MFMA n / A-row m
    const int q = l >> 4;        // k-chunk / D row-quad
    const int j = l & 31;
    const int rowbase = blockIdx.x * 16;

    // ---- Phase 1: h1 A-frags into LDS: [s][j<32] 16B, elem e -> h1[row j&15][mh=8*(j>>4)+e]
    {
        const int sh = l >> 5;  // s-half this lane produces
        const float* xr = x + (size_t)(rowbase + n) * SEQB + sh * 16;
        float xs[16];
        {
            const float4* xp = (const float4*)xr;
            float4 a = xp[0], b = xp[1], c = xp[2], d = xp[3];
            xs[0]=a.x; xs[1]=a.y; xs[2]=a.z; xs[3]=a.w;
            xs[4]=b.x; xs[5]=b.y; xs[6]=b.z; xs[7]=b.w;
            xs[8]=c.x; xs[9]=c.y; xs[10]=c.z; xs[11]=c.w;
            xs[12]=d.x; xs[13]=d.y; xs[14]=d.z; xs[15]=d.w;
        }
        const int mhb = (j >> 4) * 8;
        float w1v[8], b1v[8];
        {
            float4 wa = *(const float4*)(w1 + mhb), wb = *(const float4*)(w1 + mhb + 4);
            float4 ba = *(const float4*)(b1 + mhb), bb = *(const float4*)(b1 + mhb + 4);
            w1v[0]=wa.x; w1v[1]=wa.y; w1v[2]=wa.z; w1v[3]=wa.w;
            w1v[4]=wb.x; w1v[5]=wb.y; w1v[6]=wb.z; w1v[7]=wb.w;
            b1v[0]=ba.x; b1v[1]=ba.y; b1v[2]=ba.z; b1v[3]=ba.w;
            b1v[4]=bb.x; b1v[5]=bb.y; b1v[6]=bb.z; b1v[7]=bb.w;
        }
#pragma unroll
        for (int i = 0; i < 16; ++i) {
            const int s = sh * 16 + i;
            float v[8];
#pragma unroll
            for (int e = 0; e < 8; ++e) {
                float tv = fmaf(xs[i], w1v[e], b1v[e]);
                v[e] = fmaxf(tv, 0.01f * tv);  // leaky_relu
            }
            u32x4 p;
            p.x = pack_hi(__float_as_uint(v[1]), __float_as_uint(v[0]));
            p.y = pack_hi(__float_as_uint(v[3]), __float_as_uint(v[2]));
            p.z = pack_hi(__float_as_uint(v[5]), __float_as_uint(v[4]));
            p.w = pack_hi(__float_as_uint(v[7]), __float_as_uint(v[6]));
            *(u32x4*)(smem + s * 512 + j * 16) = p;
        }
    }

    float pfA[4], pfB[4], pbA[4], pbB[4];
    const f32x4 kz = {0.0f, 0.0f, 0.0f, 0.0f};
    const float* hrd = h_mat + n * HSTR + q * 8;   // A-frag read base (16B-aligned)
    float* hwr = h_mat + (q * 4) * HSTR + n;       // D write base

#pragma unroll 1
    for (int dir = 0; dir < 2; ++dir) {
        for (int k2 = l; k2 < 16 * HSTR; k2 += 64) h_mat[k2] = 0.0f;  // h0 = 0

        const float* bhh = dir ? bhh_b : bhh_f;
        const float* bcp = (const float*)(ws + OFF_BC) + dir * 96;
        const unsigned char* phi = ws + OFF_BGH_HI + dir * 6144u + l * 16u;
        const unsigned char* plo = ws + OFF_BGH_LO + dir * 6144u + l * 16u;
        const unsigned char* pgx = ws + OFF_BGX    + dir * 6144u + l * 16u;
        s16x8 Bhi[6], Blo[6], Bx[6];
#pragma unroll
        for (int t = 0; t < 6; ++t) {
            Bhi[t] = *(const s16x8*)(phi + t * 1024);
            Blo[t] = *(const s16x8*)(plo + t * 1024);
            Bx[t]  = *(const s16x8*)(pgx + t * 1024);
        }
        // PIN the 18 fragments in VGPRs: without this the compiler re-loads
        // all of them from global memory EVERY step (observed VGPR_Count=88).
#pragma unroll
        for (int t = 0; t < 6; ++t) {
            asm volatile("" : "+v"(Bhi[t]), "+v"(Blo[t]), "+v"(Bx[t]));
        }
        const float nbrA = -(bcp[n]      + bhh[n]);
        const float nbrB = -(bcp[16 + n] + bhh[16 + n]);
        const float nbzA = -(bcp[32 + n] + bhh[32 + n]);
        const float nbzB = -(bcp[48 + n] + bhh[48 + n]);
        const float bcnA = bcp[64 + n], bcnB = bcp[80 + n];
        const float bhnA = bhh[64 + n], bhnB = bhh[80 + n];

        float hA[4] = {0, 0, 0, 0}, hB[4] = {0, 0, 0, 0};
        float pA[4] = {0, 0, 0, 0}, pB[4] = {0, 0, 0, 0};
        const int smask = dir ? 31 : 0;

#pragma unroll 1
        for (int ss = 0; ss < SEQB; ++ss) {
            const int s = ss ^ smask;
            s16x8 ax = *(const s16x8*)(smem + s * 512 + j * 16);  // h1 frag (k>=16 dead via B=0)
            s16x8 ahi, alo;
            split_pack8(hrd, ahi, alo);

            // r,z tiles: gx + gh(split) chained, one acc each
            f32x4 a0 = MFMA_B16(ax, Bx[0], kz);
            a0 = MFMA_B16(alo, Bhi[0], a0); a0 = MFMA_B16(ahi, Blo[0], a0); a0 = MFMA_B16(ahi, Bhi[0], a0);
            f32x4 a1 = MFMA_B16(ax, Bx[1], kz);
            a1 = MFMA_B16(alo, Bhi[1], a1); a1 = MFMA_B16(ahi, Blo[1], a1); a1 = MFMA_B16(ahi, Bhi[1], a1);
            f32x4 a2 = MFMA_B16(ax, Bx[2], kz);
            a2 = MFMA_B16(alo, Bhi[2], a2); a2 = MFMA_B16(ahi, Blo[2], a2); a2 = MFMA_B16(ahi, Bhi[2], a2);
            f32x4 a3 = MFMA_B16(ax, Bx[3], kz);
            a3 = MFMA_B16(alo, Bhi[3], a3); a3 = MFMA_B16(ahi, Blo[3], a3); a3 = MFMA_B16(ahi, Bhi[3], a3);
            // n tiles: gx and gh kept separate (r gates gh)
            f32x4 x4 = MFMA_B16(ax, Bx[4], kz);
            f32x4 x5 = MFMA_B16(ax, Bx[5], kz);
            f32x4 g4 = MFMA_B16(alo, Bhi[4], kz);
            g4 = MFMA_B16(ahi, Blo[4], g4); g4 = MFMA_B16(ahi, Bhi[4], g4);
            f32x4 g5 = MFMA_B16(alo, Bhi[5], kz);
            g5 = MFMA_B16(ahi, Blo[5], g5); g5 = MFMA_B16(ahi, Bhi[5], g5);

#pragma unroll
            for (int rg = 0; rg < 4; ++rg) {
                float rA = __builtin_amdgcn_rcpf(1.0f + __expf(nbrA - a0[rg]));
                float zA = __builtin_amdgcn_rcpf(1.0f + __expf(nbzA - a2[rg]));
                float tA = fmaf(rA, g4[rg] + bhnA, x4[rg] + bcnA);
                float nA = fmaf(-2.0f, __builtin_amdgcn_rcpf(1.0f + __expf(tA + tA)), 1.0f);
                hA[rg] = fmaf(zA, hA[rg] - nA, nA);
                pA[rg] += hA[rg];

                float rB = __builtin_amdgcn_rcpf(1.0f + __expf(nbrB - a1[rg]));
                float zB = __builtin_amdgcn_rcpf(1.0f + __expf(nbzB - a3[rg]));
                float tB = fmaf(rB, g5[rg] + bhnB, x5[rg] + bcnB);
                float nB = fmaf(-2.0f, __builtin_amdgcn_rcpf(1.0f + __expf(tB + tB)), 1.0f);
                hB[rg] = fmaf(zB, hB[rg] - nB, nB);
                pB[rg] += hB[rg];

                hwr[rg * HSTR]      = hA[rg];
                hwr[rg * HSTR + 16] = hB[rg];
            }
        }
        if (dir == 0) {
#pragma unroll
            for (int rg = 0; rg < 4; ++rg) { pfA[rg] = pA[rg]; pfB[rg] = pB[rg]; }
        } else {
#pragma unroll
            for (int rg = 0; rg < 4; ++rg) { pbA[rg] = pA[rg]; pbB[rg] = pB[rg]; }
        }
    }

    // ---- pooled [16][PSTR] (overlays dead h1 frags), cols: [fwd 0..31 | bwd 32..63]
#pragma unroll
    for (int rg = 0; rg < 4; ++rg) {
        const int m = q * 4 + rg;
        pooled[m * PSTR + n]      = pfA[rg] * 0.03125f;
        pooled[m * PSTR + 16 + n] = pfB[rg] * 0.03125f;
        pooled[m * PSTR + 32 + n] = pbA[rg] * 0.03125f;
        pooled[m * PSTR + 48 + n] = pbB[rg] * 0.03125f;
    }

    // ---- decoder: out[16x128] = pooled @ w_dec^T + b_dec (pooled hi/lo split)
    {
        const float* prd = pooled + n * PSTR + q * 8;
        s16x8 aQ0hi, aQ0lo, aQ1hi, aQ1lo;
        split_pack8(prd, aQ0hi, aQ0lo);
        split_pack8(prd + 32, aQ1hi, aQ1lo);
#pragma unroll
        for (int t = 0; t < 8; ++t) {
            s16x8 bd0 = *(const s16x8*)(ws + OFF_BDEC + t * 1024u + l * 16u);
            s16x8 bd1 = *(const s16x8*)(ws + OFF_BDEC + 8192u + t * 1024u + l * 16u);
            float bdv = b_dec[t * 16 + n];
            f32x4 acc = {bdv, bdv, bdv, bdv};
            acc = MFMA_B16(aQ0lo, bd0, acc);
            acc = MFMA_B16(aQ1lo, bd1, acc);
            acc = MFMA_B16(aQ0hi, bd0, acc);
            acc = MFMA_B16(aQ1hi, bd1, acc);
#pragma unroll
            for (int rg = 0; rg < 4; ++rg)
                out[(size_t)(rowbase + q * 4 + rg) * 128 + t * 16 + n] = acc[rg];
        }
    }
}

extern "C" void kernel_launch(void* const* d_in, const int* in_sizes, int n_in,
                              void* d_out, int out_size, void* d_ws, size_t ws_size,
                              hipStream_t stream)
{
    const float* x    = (const float*)d_in[0];
    const float* w1   = (const float*)d_in[1];
    const float* b1   = (const float*)d_in[2];
    const float* w2   = (const float*)d_in[3];
    const float* b2   = (const float*)d_in[4];
    const float* wihf = (const float*)d_in[5];
    const float* whhf = (const float*)d_in[6];
    const float* bihf = (const float*)d_in[7];
    const float* bhhf = (const float*)d_in[8];
    const float* wihb = (const float*)d_in[9];
    const float* whhb = (const float*)d_in[10];
    const float* bihb = (const float*)d_in[11];
    const float* bhhb = (const float*)d_in[12];
    const float* wdec = (const float*)d_in[13];
    const float* bdec = (const float*)d_in[14];
    float* out = (float*)d_out;
    unsigned char* ws = (unsigned char*)d_ws;

    const int B = in_sizes[0] / SEQB;  // 32768
    const int grid = B / 16;           // 16 rows per 64-thread (1-wave) block

    hipLaunchKernelGGL(gru_precompute_kernel, dim3(1), dim3(1024), 0, stream,
                       wihf, bihf, wihb, bihb, w2, b2, whhf, whhb, wdec, ws);
    hipLaunchKernelGGL(gru_mfma_kernel, dim3(grid), dim3(64), 0, stream,
                       x, w1, b1, bhhf, bhhb, ws, bdec, out);
}

// Round 6
// 82.590 us; speedup vs baseline: 6.5019x; 1.1234x over previous
//
#include <hip/hip_runtime.h>

// TimeTempTransformerModule: MLP(1->16->32) -> biGRU(H=32, SEQ=32) -> meanpool -> dec(64->128)
// B = 32768 rows, fp32 in/out.
//
// v5: SWAPPED-OPERAND MFMA recurrence. 1 wave = 16 rows. ZERO LDS, no barriers.
//   g^T = W @ h^T : D[m=gate][n=row]; A = weight frags (VGPR/AGPR-resident),
//   B = state frags built IN-LANE each step. The D-layout of step s IS the
//   B-layout of step s+1 under k-permutation pi(q,e) = (e<4 ? 4q+e : 4q+12+e),
//   which is baked into the precomputed A-frags (bijection over k=0..31; A and B
//   share the same slot->k map so permuting both sides is exact).
//   - gx A-frags carry the r/z biases in dead k>=16 slots (hi+lo, paired with 1.0 in B)
//   - h1 rebuilt in-lane from 8 x-regs per 8-step chunk (no LDS table)
//   - 3-term hi/lo split for gh (Whi*Hhi + Whi*Hlo + Wlo*Hhi), rne for gx/h1/dec
// Precompute kernel folds Wc = w_ih@w2, bc = w_ih@b2 + b_ih, and emits all
// permuted A-frags (gh hi/lo, gx+bias, decoder) into ws.
//
// (Round 5 bench was lost to an unresponsive container; identical resubmission.)

#define SEQB 32
#define NH   16
#define DH   32

typedef __attribute__((ext_vector_type(4))) float f32x4;
typedef __attribute__((ext_vector_type(8))) short s16x8;
typedef __attribute__((ext_vector_type(4))) unsigned int u32x4;

#define MFMA_B16(a, b, c) __builtin_amdgcn_mfma_f32_16x16x32_bf16((a), (b), (c), 0, 0, 0)

// ws layout (bytes)
#define OFF_AHI  0u        // [dir][t<6][lane<64] 16B  gh weights hi (trunc)
#define OFF_ALO  12288u    // [dir][t<6][lane] 16B     gh weights lo (rne resid)
#define OFF_AGX  24576u    // [dir][t<6][lane] 16B     gx weights (rne) + bias slots
#define OFF_ADEC 36864u    // [kc<2][t<8][lane] 16B    decoder weights (rne)
#define OFF_WC   53248u    // [dir][96][16] f32 temp
#define OFF_BC   65536u    // [dir][96] f32 temp

__device__ __forceinline__ unsigned short bf16_rne(float x) {
    unsigned u = __float_as_uint(x);
    return (unsigned short)((u + 0x7fffu + ((u >> 16) & 1u)) >> 16);
}
// (a & 0xffff0000) | (b >> 16)  -- packs bf16(b) into lo16, bf16(a) into hi16 (trunc)
__device__ __forceinline__ unsigned pack_hi(unsigned a, unsigned b) {
    return __builtin_amdgcn_perm(a, b, 0x07060302u);
}
__device__ __forceinline__ int kperm(int q, int e) {  // pi(q,e)
    return (e < 4) ? (4 * q + e) : (4 * q + 12 + e);
}

__global__ __launch_bounds__(1024) void gru_precompute_kernel(
    const float* __restrict__ w_ih_f, const float* __restrict__ b_ih_f,
    const float* __restrict__ w_ih_b, const float* __restrict__ b_ih_b,
    const float* __restrict__ w2, const float* __restrict__ b2,
    const float* __restrict__ whh_f, const float* __restrict__ whh_b,
    const float* __restrict__ bhh_f, const float* __restrict__ bhh_b,
    const float* __restrict__ w_dec,
    unsigned char* __restrict__ ws)
{
    const int t = threadIdx.x;
    float* WC = (float*)(ws + OFF_WC);
    float* BC = (float*)(ws + OFF_BC);

    if (t < 192) {  // Wc = w_ih@w2 [96x16], bc = w_ih@b2 + b_ih
        const int dir = t / 96, g = t % 96;
        const float* wih = dir ? w_ih_b : w_ih_f;
        const float* bih = dir ? b_ih_b : b_ih_f;
        float acc[NH];
#pragma unroll
        for (int m = 0; m < NH; ++m) acc[m] = 0.0f;
        float ab = bih[g];
        for (int d = 0; d < DH; ++d) {
            float wv = wih[g * DH + d];
            ab = fmaf(wv, b2[d], ab);
#pragma unroll
            for (int m = 0; m < NH; ++m) acc[m] = fmaf(wv, w2[d * NH + m], acc[m]);
        }
#pragma unroll
        for (int m = 0; m < NH; ++m) WC[(dir * 96 + g) * NH + m] = acc[m];
        BC[dir * 96 + g] = ab;
    }
    __syncthreads();

    if (t < 768) {  // gh A-frags (hi/lo, k-permuted) + gx A-frags (rne + bias slots)
        const int dir = t / 384, r = t % 384, tt = r / 64, l = r % 64;
        const int gate = tt * 16 + (l & 15);
        const int q = l >> 4;
        const float* whh = dir ? whh_b : whh_f;
        const float* bhh = dir ? bhh_b : bhh_f;
        unsigned short h8[8], l8[8], g8[8];
#pragma unroll
        for (int e = 0; e < 8; ++e) {
            const int u = kperm(q, e);
            float w = whh[gate * DH + u];
            unsigned ub = __float_as_uint(w);
            h8[e] = (unsigned short)(ub >> 16);
            l8[e] = bf16_rne(w - __uint_as_float(ub & 0xffff0000u));
            float gxv = (e < 4) ? WC[(dir * 96 + gate) * NH + 4 * q + e] : 0.0f;
            g8[e] = bf16_rne(gxv);
        }
        // bias slots: (q=0,e=4) hi, (q=1,e=4) lo; pairs with constant 1.0 in B
        const float bias = BC[dir * 96 + gate] + ((gate < 64) ? bhh[gate] : 0.0f);
        const unsigned bb = __float_as_uint(bias);
        if (q == 0) g8[4] = (unsigned short)(bb >> 16);
        if (q == 1) g8[4] = bf16_rne(bias - __uint_as_float(bb & 0xffff0000u));

        unsigned short* dh = (unsigned short*)(ws + OFF_AHI + dir * 6144u + tt * 1024u + l * 16u);
        unsigned short* dl = (unsigned short*)(ws + OFF_ALO + dir * 6144u + tt * 1024u + l * 16u);
        unsigned short* dg = (unsigned short*)(ws + OFF_AGX + dir * 6144u + tt * 1024u + l * 16u);
#pragma unroll
        for (int e = 0; e < 8; ++e) { dh[e] = h8[e]; dl[e] = l8[e]; dg[e] = g8[e]; }
    }
    {  // decoder A-frags: A[out][k] k-permuted, k = pi(q,e) + 32*kc
        const int kc = t / 512, r = t % 512, tt = r / 64, l = r % 64;
        const int outn = tt * 16 + (l & 15);
        const int q = l >> 4;
        unsigned short* dd = (unsigned short*)(ws + OFF_ADEC + kc * 8192u + tt * 1024u + l * 16u);
#pragma unroll
        for (int e = 0; e < 8; ++e)
            dd[e] = bf16_rne(w_dec[outn * 64 + kperm(q, e) + 32 * kc]);
    }
}

__global__ __launch_bounds__(64, 2) void gru_mfma_kernel(
    const float* __restrict__ x,
    const float* __restrict__ w1, const float* __restrict__ b1,
    const float* __restrict__ bhh_f, const float* __restrict__ bhh_b,
    const unsigned char* __restrict__ ws,
    const float* __restrict__ b_dec,
    float* __restrict__ out)
{
    const int l = threadIdx.x;
    const int n = l & 15;   // batch row (D col / B col)
    const int q = l >> 4;   // k-quad / D row-quad
    const int rowbase = blockIdx.x * 16;
    const float* xr = x + (size_t)(rowbase + n) * SEQB;

    const float4 w1q = *(const float4*)(w1 + 4 * q);  // h1 units 4q..4q+3
    const float4 b1q = *(const float4*)(b1 + 4 * q);

    float pFL[4], pFH[4], pBL[4], pBH[4];

#pragma unroll 1
    for (int dir = 0; dir < 2; ++dir) {
        const float* bhh = dir ? bhh_b : bhh_f;
        const unsigned char* pAhi = ws + OFF_AHI + dir * 6144u + l * 16u;
        const unsigned char* pAlo = ws + OFF_ALO + dir * 6144u + l * 16u;
        const unsigned char* pAgx = ws + OFF_AGX + dir * 6144u + l * 16u;
        s16x8 Ahi[6], Alo[6], Agx[6];
#pragma unroll
        for (int tt = 0; tt < 6; ++tt) {
            Ahi[tt] = *(const s16x8*)(pAhi + tt * 1024);
            Alo[tt] = *(const s16x8*)(pAlo + tt * 1024);
            Agx[tt] = *(const s16x8*)(pAgx + tt * 1024);
        }
#pragma unroll
        for (int tt = 0; tt < 6; ++tt)
            asm volatile("" : "+v"(Ahi[tt]), "+v"(Alo[tt]), "+v"(Agx[tt]));
        // n-gate gh bias (C-init of the gh chain): gates 64+4q+rg (tile4), 80+4q+rg (tile5)
        const float4 bn0f = *(const float4*)(bhh + 64 + 4 * q);
        const float4 bn1f = *(const float4*)(bhh + 80 + 4 * q);
        const f32x4 bhn0 = {bn0f.x, bn0f.y, bn0f.z, bn0f.w};
        const f32x4 bhn1 = {bn1f.x, bn1f.y, bn1f.z, bn1f.w};

        float hL[4] = {0, 0, 0, 0}, hH[4] = {0, 0, 0, 0};
        float pL[4] = {0, 0, 0, 0}, pH[4] = {0, 0, 0, 0};

#pragma unroll 1
        for (int blk = 0; blk < 4; ++blk) {
            const int bb = dir ? 3 - blk : blk;
            const float4 xa = *(const float4*)(xr + bb * 8);
            const float4 xb = *(const float4*)(xr + bb * 8 + 4);
            const float raw[8] = {xa.x, xa.y, xa.z, xa.w, xb.x, xb.y, xb.z, xb.w};
            float xs[8];
#pragma unroll
            for (int i = 0; i < 8; ++i) xs[i] = dir ? raw[7 - i] : raw[i];

#pragma unroll
            for (int i = 0; i < 8; ++i) {
                // ---- B_h1 frag: h1[row n][4q+e] e<4 (in-lane), e4=1.0 (bias), e5..7=0
                float t0 = fmaf(xs[i], w1q.x, b1q.x); t0 = fmaxf(t0, 0.01f * t0);
                float t1 = fmaf(xs[i], w1q.y, b1q.y); t1 = fmaxf(t1, 0.01f * t1);
                float t2 = fmaf(xs[i], w1q.z, b1q.z); t2 = fmaxf(t2, 0.01f * t2);
                float t3 = fmaf(xs[i], w1q.w, b1q.w); t3 = fmaxf(t3, 0.01f * t3);
                u32x4 ub1;
                ub1.x = pack_hi(__float_as_uint(t1), __float_as_uint(t0));
                ub1.y = pack_hi(__float_as_uint(t3), __float_as_uint(t2));
                ub1.z = 0x00003F80u;  // e4 = 1.0 (bias partner), e5 = 0
                ub1.w = 0u;           // e6, e7 = 0
                const s16x8 Bh1 = __builtin_bit_cast(s16x8, ub1);

                // ---- B_h frags hi/lo from in-lane h state (u-order: L=4q+rg, H=16+4q+rg)
                unsigned uL0 = __float_as_uint(hL[0]), uL1 = __float_as_uint(hL[1]);
                unsigned uL2 = __float_as_uint(hL[2]), uL3 = __float_as_uint(hL[3]);
                unsigned uH0 = __float_as_uint(hH[0]), uH1 = __float_as_uint(hH[1]);
                unsigned uH2 = __float_as_uint(hH[2]), uH3 = __float_as_uint(hH[3]);
                u32x4 phh;
                phh.x = pack_hi(uL1, uL0); phh.y = pack_hi(uL3, uL2);
                phh.z = pack_hi(uH1, uH0); phh.w = pack_hi(uH3, uH2);
                float lL0 = hL[0] - __uint_as_float(uL0 & 0xffff0000u);
                float lL1 = hL[1] - __uint_as_float(uL1 & 0xffff0000u);
                float lL2 = hL[2] - __uint_as_float(uL2 & 0xffff0000u);
                float lL3 = hL[3] - __uint_as_float(uL3 & 0xffff0000u);
                float lH0 = hH[0] - __uint_as_float(uH0 & 0xffff0000u);
                float lH1 = hH[1] - __uint_as_float(uH1 & 0xffff0000u);
                float lH2 = hH[2] - __uint_as_float(uH2 & 0xffff0000u);
                float lH3 = hH[3] - __uint_as_float(uH3 & 0xffff0000u);
                u32x4 phl;
                phl.x = pack_hi(__float_as_uint(lL1), __float_as_uint(lL0));
                phl.y = pack_hi(__float_as_uint(lL3), __float_as_uint(lL2));
                phl.z = pack_hi(__float_as_uint(lH1), __float_as_uint(lH0));
                phl.w = pack_hi(__float_as_uint(lH3), __float_as_uint(lH2));
                const s16x8 Bhhi = __builtin_bit_cast(s16x8, phh);
                const s16x8 Bhlo = __builtin_bit_cast(s16x8, phl);

                const f32x4 z4 = {0.0f, 0.0f, 0.0f, 0.0f};
                // r tiles (gates 0..15 / 16..31): gx+bias then 3-term gh, one chain
                f32x4 a0 = MFMA_B16(Agx[0], Bh1, z4);
                a0 = MFMA_B16(Alo[0], Bhhi, a0); a0 = MFMA_B16(Ahi[0], Bhlo, a0); a0 = MFMA_B16(Ahi[0], Bhhi, a0);
                f32x4 a1 = MFMA_B16(Agx[1], Bh1, z4);
                a1 = MFMA_B16(Alo[1], Bhhi, a1); a1 = MFMA_B16(Ahi[1], Bhlo, a1); a1 = MFMA_B16(Ahi[1], Bhhi, a1);
                // z tiles
                f32x4 a2 = MFMA_B16(Agx[2], Bh1, z4);
                a2 = MFMA_B16(Alo[2], Bhhi, a2); a2 = MFMA_B16(Ahi[2], Bhlo, a2); a2 = MFMA_B16(Ahi[2], Bhhi, a2);
                f32x4 a3 = MFMA_B16(Agx[3], Bh1, z4);
                a3 = MFMA_B16(Alo[3], Bhhi, a3); a3 = MFMA_B16(Ahi[3], Bhlo, a3); a3 = MFMA_B16(Ahi[3], Bhhi, a3);
                // n tiles: gx (with bcn in bias slot) and gh (C-init = bhn) kept separate
                f32x4 x4a = MFMA_B16(Agx[4], Bh1, z4);
                f32x4 x5a = MFMA_B16(Agx[5], Bh1, z4);
                f32x4 g4 = MFMA_B16(Alo[4], Bhhi, bhn0);
                g4 = MFMA_B16(Ahi[4], Bhlo, g4); g4 = MFMA_B16(Ahi[4], Bhhi, g4);
                f32x4 g5 = MFMA_B16(Alo[5], Bhhi, bhn1);
                g5 = MFMA_B16(Ahi[5], Bhlo, g5); g5 = MFMA_B16(Ahi[5], Bhhi, g5);

                // ---- activations + state update (all in-lane, fp32)
#pragma unroll
                for (int rg = 0; rg < 4; ++rg) {
                    float rL = __builtin_amdgcn_rcpf(1.0f + __expf(-a0[rg]));
                    float zL = __builtin_amdgcn_rcpf(1.0f + __expf(-a2[rg]));
                    float tL = fmaf(rL, g4[rg], x4a[rg]);
                    float nL = fmaf(-2.0f, __builtin_amdgcn_rcpf(1.0f + __expf(tL + tL)), 1.0f);
                    hL[rg] = fmaf(zL, hL[rg] - nL, nL);
                    pL[rg] += hL[rg];

                    float rH = __builtin_amdgcn_rcpf(1.0f + __expf(-a1[rg]));
                    float zH = __builtin_amdgcn_rcpf(1.0f + __expf(-a3[rg]));
                    float tH = fmaf(rH, g5[rg], x5a[rg]);
                    float nH = fmaf(-2.0f, __builtin_amdgcn_rcpf(1.0f + __expf(tH + tH)), 1.0f);
                    hH[rg] = fmaf(zH, hH[rg] - nH, nH);
                    pH[rg] += hH[rg];
                }
            }
        }
        if (dir == 0) {
#pragma unroll
            for (int rg = 0; rg < 4; ++rg) { pFL[rg] = pL[rg]; pFH[rg] = pH[rg]; }
        } else {
#pragma unroll
            for (int rg = 0; rg < 4; ++rg) { pBL[rg] = pL[rg]; pBH[rg] = pH[rg]; }
        }
    }

    // ---- decoder: out[16x128] = pooled[16x64] @ w_dec^T + b_dec (swapped MFMA)
    {
#pragma unroll
        for (int rg = 0; rg < 4; ++rg) {
            pFL[rg] *= 0.03125f; pFH[rg] *= 0.03125f;
            pBL[rg] *= 0.03125f; pBH[rg] *= 0.03125f;
        }
        u32x4 pfh, pfl, pbh, pbl;
        unsigned v0, v1, v2, v3;
        v0 = __float_as_uint(pFL[0]); v1 = __float_as_uint(pFL[1]);
        v2 = __float_as_uint(pFL[2]); v3 = __float_as_uint(pFL[3]);
        pfh.x = pack_hi(v1, v0); pfh.y = pack_hi(v3, v2);
        pfl.x = pack_hi(__float_as_uint(pFL[1] - __uint_as_float(v1 & 0xffff0000u)),
                        __float_as_uint(pFL[0] - __uint_as_float(v0 & 0xffff0000u)));
        pfl.y = pack_hi(__float_as_uint(pFL[3] - __uint_as_float(v3 & 0xffff0000u)),
                        __float_as_uint(pFL[2] - __uint_as_float(v2 & 0xffff0000u)));
        v0 = __float_as_uint(pFH[0]); v1 = __float_as_uint(pFH[1]);
        v2 = __float_as_uint(pFH[2]); v3 = __float_as_uint(pFH[3]);
        pfh.z = pack_hi(v1, v0); pfh.w = pack_hi(v3, v2);
        pfl.z = pack_hi(__float_as_uint(pFH[1] - __uint_as_float(v1 & 0xffff0000u)),
                        __float_as_uint(pFH[0] - __uint_as_float(v0 & 0xffff0000u)));
        pfl.w = pack_hi(__float_as_uint(pFH[3] - __uint_as_float(v3 & 0xffff0000u)),
                        __float_as_uint(pFH[2] - __uint_as_float(v2 & 0xffff0000u)));
        v0 = __float_as_uint(pBL[0]); v1 = __float_as_uint(pBL[1]);
        v2 = __float_as_uint(pBL[2]); v3 = __float_as_uint(pBL[3]);
        pbh.x = pack_hi(v1, v0); pbh.y = pack_hi(v3, v2);
        pbl.x = pack_hi(__float_as_uint(pBL[1] - __uint_as_float(v1 & 0xffff0000u)),
                        __float_as_uint(pBL[0] - __uint_as_float(v0 & 0xffff0000u)));
        pbl.y = pack_hi(__float_as_uint(pBL[3] - __uint_as_float(v3 & 0xffff0000u)),
                        __float_as_uint(pBL[2] - __uint_as_float(v2 & 0xffff0000u)));
        v0 = __float_as_uint(pBH[0]); v1 = __float_as_uint(pBH[1]);
        v2 = __float_as_uint(pBH[2]); v3 = __float_as_uint(pBH[3]);
        pbh.z = pack_hi(v1, v0); pbh.w = pack_hi(v3, v2);
        pbl.z = pack_hi(__float_as_uint(pBH[1] - __uint_as_float(v1 & 0xffff0000u)),
                        __float_as_uint(pBH[0] - __uint_as_float(v0 & 0xffff0000u)));
        pbl.w = pack_hi(__float_as_uint(pBH[3] - __uint_as_float(v3 & 0xffff0000u)),
                        __float_as_uint(pBH[2] - __uint_as_float(v2 & 0xffff0000u)));
        const s16x8 BpFh = __builtin_bit_cast(s16x8, pfh);
        const s16x8 BpFl = __builtin_bit_cast(s16x8, pfl);
        const s16x8 BpBh = __builtin_bit_cast(s16x8, pbh);
        const s16x8 BpBl = __builtin_bit_cast(s16x8, pbl);

#pragma unroll
        for (int tt = 0; tt < 8; ++tt) {
            const s16x8 A0 = *(const s16x8*)(ws + OFF_ADEC + tt * 1024u + l * 16u);
            const s16x8 A1 = *(const s16x8*)(ws + OFF_ADEC + 8192u + tt * 1024u + l * 16u);
            const float4 bd = *(const float4*)(b_dec + tt * 16 + 4 * q);
            f32x4 acc = {bd.x, bd.y, bd.z, bd.w};
            acc = MFMA_B16(A0, BpFl, acc);
            acc = MFMA_B16(A1, BpBl, acc);
            acc = MFMA_B16(A0, BpFh, acc);
            acc = MFMA_B16(A1, BpBh, acc);
            *(float4*)(out + (size_t)(rowbase + n) * 128 + tt * 16 + 4 * q) =
                make_float4(acc[0], acc[1], acc[2], acc[3]);
        }
    }
}

extern "C" void kernel_launch(void* const* d_in, const int* in_sizes, int n_in,
                              void* d_out, int out_size, void* d_ws, size_t ws_size,
                              hipStream_t stream)
{
    const float* x    = (const float*)d_in[0];
    const float* w1   = (const float*)d_in[1];
    const float* b1   = (const float*)d_in[2];
    const float* w2   = (const float*)d_in[3];
    const float* b2   = (const float*)d_in[4];
    const float* wihf = (const float*)d_in[5];
    const float* whhf = (const float*)d_in[6];
    const float* bihf = (const float*)d_in[7];
    const float* bhhf = (const float*)d_in[8];
    const float* wihb = (const float*)d_in[9];
    const float* whhb = (const float*)d_in[10];
    const float* bihb = (const float*)d_in[11];
    const float* bhhb = (const float*)d_in[12];
    const float* wdec = (const float*)d_in[13];
    const float* bdec = (const float*)d_in[14];
    float* out = (float*)d_out;
    unsigned char* ws = (unsigned char*)d_ws;

    const int B = in_sizes[0] / SEQB;  // 32768
    const int grid = B / 16;           // 16 rows per 64-thread (1-wave) block

    hipLaunchKernelGGL(gru_precompute_kernel, dim3(1), dim3(1024), 0, stream,
                       wihf, bihf, wihb, bihb, w2, b2, whhf, whhb, bhhf, bhhb, wdec, ws);
    hipLaunchKernelGGL(gru_mfma_kernel, dim3(grid), dim3(64), 0, stream,
                       x, w1, b1, bhhf, bhhb, ws, bdec, out);
}